// Round 17
// baseline (137.556 us; speedup 1.0000x reference)
//
#include <hip/hip_runtime.h>
#include <hip/hip_bf16.h>

// Problem constants (B=1)
#define S_LEN 2048
#define E_DIM 1024
#define NH    16
#define HD    64
#define SM_SCALE 0.5f
#define LOG2E 1.44269504088896340736f

typedef short bf16x8_t  __attribute__((ext_vector_type(8)));    // 8 bf16 = 4 VGPRs
typedef float f32x4_t   __attribute__((ext_vector_type(4)));
typedef float f32x16_t  __attribute__((ext_vector_type(16)));
typedef __bf16 bf16x4_t __attribute__((ext_vector_type(4)));

static __device__ __forceinline__ unsigned short f2bf_bits(float f) {
    return __builtin_bit_cast(unsigned short, (__bf16)f);
}

// v_cvt_pk_bf16_f32: dst.lo = bf16(lo), dst.hi = bf16(hi)  (RNE, same as (__bf16) cast)
static __device__ __forceinline__ unsigned int cvt_pk_bf16(float lo, float hi) {
    unsigned int r;
    asm("v_cvt_pk_bf16_f32 %0, %1, %2" : "=v"(r) : "v"(lo), "v"(hi));
    return r;
}

// async global->LDS, 16B per lane, dest = wave-uniform base + lane*16
#define GLD16(gp, lp) __builtin_amdgcn_global_load_lds(                       \
    (const __attribute__((address_space(1))) void*)(gp),                      \
    (__attribute__((address_space(3))) void*)(lp), 16, 0, 0)

// -------------------------------------------- merged prep: W^T + x->bf16
__global__ void k_prep(const float* __restrict__ x,
                       const float* __restrict__ Wq, const float* __restrict__ Wk,
                       const float* __restrict__ Wv, const float* __restrict__ Wo,
                       __bf16* __restrict__ xb, __bf16* __restrict__ wt) {
    const int z = blockIdx.z;
    if (z < 4) {
        __shared__ float tile[32][33];
        const float* W = z == 0 ? Wq : z == 1 ? Wk : z == 2 ? Wv : Wo;
        __bf16* o = wt + (size_t)z * E_DIM * E_DIM;
        const int tx = threadIdx.x, ty = threadIdx.y;
        const int bx = blockIdx.x * 32, by = blockIdx.y * 32;
#pragma unroll
        for (int j = 0; j < 32; j += 8)
            tile[ty + j][tx] = W[(size_t)(by + ty + j) * E_DIM + bx + tx];
        __syncthreads();
#pragma unroll
        for (int j = 0; j < 32; j += 8)
            o[(size_t)(bx + ty + j) * E_DIM + by + tx] = (__bf16)tile[tx][ty + j];
    } else {
        const int bid = (z - 4) * 1024 + blockIdx.y * 32 + blockIdx.x;
        const int tid = threadIdx.y * 32 + threadIdx.x;
        const int i = bid * 256 + tid;
        const float4 v = ((const float4*)x)[i];
        bf16x4_t o4;
        o4.x = (__bf16)v.x; o4.y = (__bf16)v.y; o4.z = (__bf16)v.z; o4.w = (__bf16)v.w;
        ((bf16x4_t*)xb)[i] = o4;
    }
}

// ------------------------------------------------------- QKV projection GEMM
// NOW 128x64 tile (was 128x128): grid 16x16x3 = 768 blocks = 3.0 blocks/CU
// uniform (was 384 = 1.5/CU imbalanced) x 8 waves = 24 waves/CU — the
// R16 win-shape (independent 8-wave blocks, not bigger barrier groups).
// BK=32, single-buffer two-barrier loop, 512 threads. Wave grid 2m x 4n,
// sub-tile 64x16: af[4], bfr[1], acc[4], 4 MFMA/step/wave. LDS 12KB.
// Staging: wave w GLD16s As chunk w (rows w*16..+15); waves 4..7 also
// GLD16 Bs chunk w-4. B-panel fetched 2x (L2-resident wt, issue cost only).
// Q scale folds SM_SCALE*LOG2E -> attn uses raw exp2.
// Epilogue scatters into 32x32x16-MFMA operand-native layout:
//   Q (B-op): [h][qt][rb2][kc4][lane64][j8]  rb=(s&63)>>5, lane=(s&31)+((d>>3)&1)*32, kc=d>>4, j=d&7
//   K (A-op): same index function as Q
//   V (A-op, V^T): [h][kt][db2][kc4][lane64][j8] db=d>>5, lane=(d&31)+((key>>3)&1)*32, kc=(key&63)>>4, j=key&7
__global__ __launch_bounds__(512) void k_gemm_qkv(
    const __bf16* __restrict__ xb, const __bf16* __restrict__ wt,
    const float* __restrict__ bq, const float* __restrict__ bk, const float* __restrict__ bv,
    __bf16* __restrict__ qkv) {
    __shared__ __align__(16) unsigned short As[128 * 32];   // 8 KB
    __shared__ __align__(16) unsigned short Bs[64 * 32];    // 4 KB

    const int z = blockIdx.z;
    const __bf16* Bt = wt + (size_t)z * E_DIM * E_DIM;      // W^T [n][k]
    const float* bias = z == 0 ? bq : z == 1 ? bk : bv;
    __bf16* out = qkv + (size_t)z * NH * S_LEN * HD;

    const int tid = threadIdx.x, w = tid >> 6, l = tid & 63;
    const int lm = l & 15, q4 = l >> 4;
    const int bm = blockIdx.y, bn = blockIdx.x;
    const int wm = w >> 2, wn = w & 3;                      // 2x4 waves, 64x16 each

    const int sm = (w << 4) + (l >> 2);                     // As row 0..127
    const int smB = ((w & 3) << 4) + (l >> 2);              // Bs row 0..63 (w>=4)
    const int skk = (l & 3) << 3;
    const __bf16* Ag = xb + (size_t)(bm * 128 + sm) * E_DIM + skk;
    const __bf16* Bg = Bt + (size_t)(bn * 64 + smB) * E_DIM + skk;  // deref w>=4 only
    unsigned short* AsW = As + (w << 9);                    // chunk = 1KB
    unsigned short* BsW = Bs + ((w & 3) << 9);

    f32x4_t acc[4];
#pragma unroll
    for (int i = 0; i < 4; i++) { acc[i].x = 0.f; acc[i].y = 0.f; acc[i].z = 0.f; acc[i].w = 0.f; }

    for (int k0 = 0; k0 < E_DIM; k0 += 32) {
        __syncthreads();
        GLD16(Ag + k0, AsW);
        if (w >= 4) GLD16(Bg + k0, BsW);
        __syncthreads();

        bf16x8_t af[4], bfr;
#pragma unroll
        for (int mt = 0; mt < 4; mt++)
            af[mt] = *(const bf16x8_t*)&As[(wm * 64 + mt * 16 + lm) * 32 + q4 * 8];
        bfr = *(const bf16x8_t*)&Bs[(wn * 16 + lm) * 32 + q4 * 8];
#pragma unroll
        for (int mt = 0; mt < 4; mt++)
            acc[mt] = __builtin_amdgcn_mfma_f32_16x16x32_bf16(af[mt], bfr, acc[mt], 0, 0, 0);
    }

    // C row s = bm*128 + wm*64 + mt*16 + q4*4 + i ; col n = bn*64 + wn*16 + lm
    {
        const int n = bn * 64 + wn * 16 + lm;
        const float bval = bias[n];
        const int h = n >> 6, d = n & 63;
        const int tile0 = bm * 2 + wm;          // s>>6
        if (z == 2) {
            // V A-op-native: key = mt*16 + q4*4 + i (local in tile)
            const int db = d >> 5, dl = d & 31;
#pragma unroll
            for (int mt = 0; mt < 4; mt++) {
                __bf16* ob = out + (((size_t)h * 32 + tile0) * 8 + db * 4 + mt) * 512
                                 + (dl + (q4 >> 1) * 32) * 8 + (q4 & 1) * 4;
                union { unsigned short s4[4]; uint2 u; } pk;
#pragma unroll
                for (int i = 0; i < 4; i++) pk.s4[i] = f2bf_bits(acc[mt][i] + bval);
                *(uint2*)ob = pk.u;
            }
        } else {
            // Q/K op-native: s_local = mt*16 + q4*4 + i, rb = mt>>1
            // Q scale = SM_SCALE * LOG2E: attn computes exp2(S) = exp(S_orig*SM_SCALE)
            const float scale = (z == 0) ? (SM_SCALE * LOG2E) : 1.0f;
            const int kc = d >> 4, khalf = (d >> 3) & 1, j = d & 7;
#pragma unroll
            for (int mt = 0; mt < 4; mt++) {
                __bf16* ob = out + (((size_t)h * 32 + tile0) * 8 + (mt >> 1) * 4 + kc) * 512
                                 + ((mt & 1) * 16 + q4 * 4 + khalf * 32) * 8 + j;
#pragma unroll
                for (int i = 0; i < 4; i++)
                    ob[i * 8] = (__bf16)((acc[mt][i] + bval) * scale);
            }
        }
    }
}

// ------------------------------------------------------------- attention
// R14 form (session best): 8-wave key-quarter split, 512 blocks x 512
// threads. Wave = (rh = w&1, kq = w>>1): rh picks 32 of the block's 64
// q-rows, kq picks 32 of the 128-key staging tile. 4 waves/SIMD (16
// waves/CU). Chunk maps: K chunk = kq*4+kc; V chunk = (kq>>1)*8 + db*4 +
// (kq&1)*2 + c. Causal: off = rowmin-base; skip iff off<-31, triangular iff
// off<=30. 4-way key partials combine linearly (no-max softmax, scores
// bounded). log2e pre-folded into Q -> raw exp2.
__global__ __launch_bounds__(512) void k_attn(
    const __bf16* __restrict__ Qf, const __bf16* __restrict__ Kf, const __bf16* __restrict__ Vf,
    __bf16* __restrict__ attn) {
    __shared__ __align__(16) unsigned short KVs[2][2][8192];  // [buf][K/V][16KB = 128 keys]

    // work-balanced swizzle: long q-tiles dispatched first
    const int b = blockIdx.x;
    int qt, h;
    if (b < 256) { qt = 16 + (b >> 4); h = b & 15; }
    else         { qt = 15 - ((b - 256) >> 4); h = (b - 256) & 15; }

    const int tid = threadIdx.x, w = tid >> 6, l = tid & 63;
    const int rh = w & 1, kq = w >> 1;          // 2 row-halves x 4 key-quarters
    const int l31 = l & 31, lh = l >> 5;

    const __bf16* Qb = Qf + ((size_t)h * 32 + qt) * 4096;
    const __bf16* Kb = Kf + (size_t)h * 32 * 4096;
    const __bf16* Vb = Vf + (size_t)h * 32 * 4096;

    // stage 128-key tile t: 16 K chunks + 16 V chunks of 1KB; wave w does 4
    auto stage = [&](int t, int buf) {
        const __bf16* Kg = Kb + (size_t)t * 8192;
        const __bf16* Vg = Vb + (size_t)t * 8192;
        GLD16(Kg + (w << 9) + l * 8,       &KVs[buf][0][(w << 9) + l * 8]);
        GLD16(Kg + ((w + 8) << 9) + l * 8, &KVs[buf][0][((w + 8) << 9) + l * 8]);
        GLD16(Vg + (w << 9) + l * 8,       &KVs[buf][1][(w << 9) + l * 8]);
        GLD16(Vg + ((w + 8) << 9) + l * 8, &KVs[buf][1][((w + 8) << 9) + l * 8]);
    };

    // Q B-frags pinned (pre-scaled by SM_SCALE*log2e): rows rh*32..+31
    bf16x8_t qf[4];
#pragma unroll
    for (int kc = 0; kc < 4; kc++)
        qf[kc] = *(const bf16x8_t*)(Qb + ((rh * 4 + kc) << 9) + l * 8);

    float lacc = 0.f;
    f32x16_t oacc[2];
#pragma unroll
    for (int db = 0; db < 2; db++)
#pragma unroll
        for (int r = 0; r < 16; r++) oacc[db][r] = 0.f;

    stage(0, 0);
    __syncthreads();

    const int ntiles = (qt >> 1) + 1;           // 128-key tiles to cover (qt+1)*64 keys
    const int rowmin = qt * 64 + rh * 32;       // this wave's lowest q-row

    for (int t = 0; t < ntiles; t++) {
        const int bb = t & 1;
        if (t + 1 < ntiles) stage(t + 1, bb ^ 1);

        const int base = t * 128 + kq * 32;     // wave's key base
        const int off = rowmin - base;          // >=31 plain; -31..30 tri; <-31 skip
        if (off >= -31) {
            // S^T = K·Q^T : D[keyl = (reg&3)+8*(reg>>2)+4*lh][row = l31]
            f32x16_t st;
#pragma unroll
            for (int r = 0; r < 16; r++) st[r] = 0.f;
            __builtin_amdgcn_s_setprio(1);
#pragma unroll
            for (int kc = 0; kc < 4; kc++) {
                bf16x8_t kf = *(const bf16x8_t*)&KVs[bb][0][((kq * 4 + kc) << 9) + l * 8];
                st = __builtin_amdgcn_mfma_f32_32x32x16_bf16(kf, qf[kc], st, 0, 0, 0);
            }
            __builtin_amdgcn_s_setprio(0);
            // exp2 (log2e folded into Q) + causal mask when tri
            if (off <= 30) {
#pragma unroll
                for (int r = 0; r < 16; r++) {
                    const int keyl = (r & 3) + 8 * (r >> 2) + 4 * lh;
                    st[r] = (keyl > off + l31) ? 0.f : __builtin_amdgcn_exp2f(st[r]);
                }
            } else {
#pragma unroll
                for (int r = 0; r < 16; r++) st[r] = __builtin_amdgcn_exp2f(st[r]);
            }
#pragma unroll
            for (int r = 0; r < 16; r++) lacc += st[r];
            // O^T += V^T·P : A = V frags, B = P frags built fully in-register.
            // c covers keys kq*32 + c*16 + {0..15}; st regs c*8..c*8+7 hold them.
#pragma unroll
            for (int c = 0; c < 2; c++) {
                unsigned int v0 = cvt_pk_bf16(st[c * 8 + 0], st[c * 8 + 1]);
                unsigned int v1 = cvt_pk_bf16(st[c * 8 + 2], st[c * 8 + 3]);
                unsigned int v2 = cvt_pk_bf16(st[c * 8 + 4], st[c * 8 + 5]);
                unsigned int v3 = cvt_pk_bf16(st[c * 8 + 6], st[c * 8 + 7]);
                // a' = [a.lo | b.lo], b' = [a.hi | b.hi] across the lane halves
                asm("v_permlane32_swap_b32 %0, %1" : "+v"(v0), "+v"(v2));
                asm("v_permlane32_swap_b32 %0, %1" : "+v"(v1), "+v"(v3));
                union { unsigned int u4[4]; bf16x8_t v; } pku;
                pku.u4[0] = v0; pku.u4[1] = v1; pku.u4[2] = v2; pku.u4[3] = v3;
                __builtin_amdgcn_s_setprio(1);
#pragma unroll
                for (int db = 0; db < 2; db++) {
                    const int vchunk = ((kq >> 1) * 8) + db * 4 + ((kq & 1) * 2) + c;
                    bf16x8_t vf = *(const bf16x8_t*)&KVs[bb][1][(vchunk << 9) + l * 8];
                    oacc[db] = __builtin_amdgcn_mfma_f32_32x32x16_bf16(vf, pku.v, oacc[db], 0, 0, 0);
                }
                __builtin_amdgcn_s_setprio(0);
            }
        }
        __syncthreads();   // reads of buf bb done; prefetch of bb^1 landed
    }

    // ---- key-quarter combine (linear: no-max softmax) ----
    // KVs reusable: all waves past the final loop barrier. Ex: per-lane
    // [rh*3 + (kq-1)][lane][34]: 32 O + lacc = 52KB <= 64KB.
    float* Ex = (float*)KVs;
    if (kq > 0) {
        float* e = Ex + (((rh * 3) + (kq - 1)) * 64 + l) * 34;
#pragma unroll
        for (int db = 0; db < 2; db++)
#pragma unroll
            for (int r = 0; r < 16; r++) e[db * 16 + r] = oacc[db][r];
        e[32] = lacc;
    }
    __syncthreads();
    if (kq == 0) {
#pragma unroll
        for (int p = 0; p < 3; p++) {
            const float* e = Ex + (((rh * 3) + p) * 64 + l) * 34;
#pragma unroll
            for (int db = 0; db < 2; db++)
#pragma unroll
                for (int r = 0; r < 16; r++) oacc[db][r] += e[db * 16 + r];
            lacc += e[32];
        }
        lacc += __shfl_xor(lacc, 32, 64);   // lanes l31 / l31+32 hold same row
        const float rl = 1.f / lacc;
        const int row = qt * 64 + rh * 32 + l31;
#pragma unroll
        for (int db = 0; db < 2; db++)
#pragma unroll
            for (int a = 0; a < 4; a++) {
                union { unsigned short s4[4]; uint2 u; } pk;
#pragma unroll
                for (int i = 0; i < 4; i++) pk.s4[i] = f2bf_bits(oacc[db][a * 4 + i] * rl);
                *(uint2*)(attn + (size_t)row * E_DIM + h * HD + db * 32 + a * 8 + lh * 4) = pk.u;
            }
    }
}

// --------------------------------------------------------- output projection
// R16 form (session best): 64x64 tile, grid 16x32 = 512 blocks = 2
// independent blocks/CU x 8 waves = 16 waves/CU. Double-buffered, 512
// threads. Wave grid 2m x 4n, sub-tile 32x16: af[2], bfr[1], acc[2],
// 2 MFMA/step/wave. Staging: waves 0..3 GLD16 As chunk w; waves 4..7
// GLD16 Bs chunk w-4. LDS 16KB.
__global__ __launch_bounds__(512) void k_gemm_out(
    const __bf16* __restrict__ A, const __bf16* __restrict__ Bt,
    const float* __restrict__ bias, float* __restrict__ out) {
    __shared__ __align__(16) unsigned short As[2][64 * 32];
    __shared__ __align__(16) unsigned short Bs[2][64 * 32];

    const int tid = threadIdx.x, w = tid >> 6, l = tid & 63;
    const int lm = l & 15, q4 = l >> 4;
    const int bm = blockIdx.y, bn = blockIdx.x;
    const int wm = w >> 2, wn = w & 3;                      // 2x4 waves, 32x16 each

    const int sc = w & 3;
    const int sm = (sc << 4) + (l >> 2);                    // chunk row 0..63
    const int skk = (l & 3) << 3;
    const __bf16* Ag = A + (size_t)(bm * 64 + sm) * E_DIM + skk;     // deref w<4 only
    const __bf16* Bg = Bt + (size_t)(bn * 64 + sm) * E_DIM + skk;    // deref w>=4 only
    const int coff = sc << 9;                               // 1KB chunk

    f32x4_t acc[2];
#pragma unroll
    for (int i = 0; i < 2; i++) { acc[i].x = 0.f; acc[i].y = 0.f; acc[i].z = 0.f; acc[i].w = 0.f; }

    if (w < 4) GLD16(Ag, &As[0][coff]);
    else       GLD16(Bg, &Bs[0][coff]);
    __syncthreads();

    for (int s = 0; s < 32; s++) {
        const int bb = s & 1;
        if (s < 31) {
            const int k0 = (s + 1) * 32;
            if (w < 4) GLD16(Ag + k0, &As[bb ^ 1][coff]);
            else       GLD16(Bg + k0, &Bs[bb ^ 1][coff]);
        }

        bf16x8_t af[2], bfr;
#pragma unroll
        for (int mt = 0; mt < 2; mt++)
            af[mt] = *(const bf16x8_t*)&As[bb][(wm * 32 + mt * 16 + lm) * 32 + q4 * 8];
        bfr = *(const bf16x8_t*)&Bs[bb][(wn * 16 + lm) * 32 + q4 * 8];
#pragma unroll
        for (int mt = 0; mt < 2; mt++)
            acc[mt] = __builtin_amdgcn_mfma_f32_16x16x32_bf16(af[mt], bfr, acc[mt], 0, 0, 0);
        __syncthreads();
    }

    {
        const int n = bn * 64 + wn * 16 + lm;
        const float bval = bias[n];
#pragma unroll
        for (int mt = 0; mt < 2; mt++) {
            const int r0 = bm * 64 + wm * 32 + mt * 16 + q4 * 4;
#pragma unroll
            for (int i = 0; i < 4; i++)
                out[(size_t)(r0 + i) * E_DIM + n] = acc[mt][i] + bval;
        }
    }
}

extern "C" void kernel_launch(void* const* d_in, const int* in_sizes, int n_in,
                              void* d_out, int out_size, void* d_ws, size_t ws_size,
                              hipStream_t stream) {
    const float* x  = (const float*)d_in[0];
    const float* Wq = (const float*)d_in[1];
    const float* bq = (const float*)d_in[2];
    const float* Wk = (const float*)d_in[3];
    const float* bk = (const float*)d_in[4];
    const float* Wv = (const float*)d_in[5];
    const float* bv = (const float*)d_in[6];
    const float* Wo = (const float*)d_in[7];
    const float* bo = (const float*)d_in[8];
    float* out = (float*)d_out;

    char* ws = (char*)d_ws;
    __bf16* xb   = (__bf16*)(ws);                        // 4 MB  x bf16 [S][E]
    __bf16* wt   = (__bf16*)(ws + ((size_t)4  << 20));   // 4x2MB [Wq^T,Wk^T,Wv^T,Wo^T] bf16
    __bf16* qkv  = (__bf16*)(ws + ((size_t)12 << 20));   // op-native Qf,Kf,Vf (4MB each)
    __bf16* attn = (__bf16*)(ws + ((size_t)24 << 20));   // 4 MB  [S][E] bf16

    k_prep<<<dim3(32, 32, 6), dim3(32, 8), 0, stream>>>(x, Wq, Wk, Wv, Wo, xb, wt);
    k_gemm_qkv<<<dim3(E_DIM / 64, S_LEN / 128, 3), 512, 0, stream>>>(xb, wt, bq, bk, bv, qkv);
    k_attn<<<dim3(512), 512, 0, stream>>>(
        qkv, qkv + (size_t)NH * S_LEN * HD, qkv + (size_t)2 * NH * S_LEN * HD, attn);
    k_gemm_out<<<dim3(E_DIM / 64, S_LEN / 64), 512, 0, stream>>>(
        attn, wt + (size_t)3 * E_DIM * E_DIM, bo, out);
}

// Round 18
// 136.022 us; speedup vs baseline: 1.0113x; 1.0113x over previous
//
#include <hip/hip_runtime.h>
#include <hip/hip_bf16.h>

// Problem constants (B=1)
#define S_LEN 2048
#define E_DIM 1024
#define NH    16
#define HD    64
#define SM_SCALE 0.5f
#define LOG2E 1.44269504088896340736f

typedef short bf16x8_t  __attribute__((ext_vector_type(8)));    // 8 bf16 = 4 VGPRs
typedef float f32x4_t   __attribute__((ext_vector_type(4)));
typedef float f32x16_t  __attribute__((ext_vector_type(16)));
typedef __bf16 bf16x4_t __attribute__((ext_vector_type(4)));

static __device__ __forceinline__ unsigned short f2bf_bits(float f) {
    return __builtin_bit_cast(unsigned short, (__bf16)f);
}

// v_cvt_pk_bf16_f32: dst.lo = bf16(lo), dst.hi = bf16(hi)  (RNE, same as (__bf16) cast)
static __device__ __forceinline__ unsigned int cvt_pk_bf16(float lo, float hi) {
    unsigned int r;
    asm("v_cvt_pk_bf16_f32 %0, %1, %2" : "=v"(r) : "v"(lo), "v"(hi));
    return r;
}

// async global->LDS, 16B per lane, dest = wave-uniform base + lane*16
#define GLD16(gp, lp) __builtin_amdgcn_global_load_lds(                       \
    (const __attribute__((address_space(1))) void*)(gp),                      \
    (__attribute__((address_space(3))) void*)(lp), 16, 0, 0)

// -------------------------------------------- merged prep: W^T + x->bf16
__global__ void k_prep(const float* __restrict__ x,
                       const float* __restrict__ Wq, const float* __restrict__ Wk,
                       const float* __restrict__ Wv, const float* __restrict__ Wo,
                       __bf16* __restrict__ xb, __bf16* __restrict__ wt) {
    const int z = blockIdx.z;
    if (z < 4) {
        __shared__ float tile[32][33];
        const float* W = z == 0 ? Wq : z == 1 ? Wk : z == 2 ? Wv : Wo;
        __bf16* o = wt + (size_t)z * E_DIM * E_DIM;
        const int tx = threadIdx.x, ty = threadIdx.y;
        const int bx = blockIdx.x * 32, by = blockIdx.y * 32;
#pragma unroll
        for (int j = 0; j < 32; j += 8)
            tile[ty + j][tx] = W[(size_t)(by + ty + j) * E_DIM + bx + tx];
        __syncthreads();
#pragma unroll
        for (int j = 0; j < 32; j += 8)
            o[(size_t)(bx + ty + j) * E_DIM + by + tx] = (__bf16)tile[tx][ty + j];
    } else {
        const int bid = (z - 4) * 1024 + blockIdx.y * 32 + blockIdx.x;
        const int tid = threadIdx.y * 32 + threadIdx.x;
        const int i = bid * 256 + tid;
        const float4 v = ((const float4*)x)[i];
        bf16x4_t o4;
        o4.x = (__bf16)v.x; o4.y = (__bf16)v.y; o4.z = (__bf16)v.z; o4.w = (__bf16)v.w;
        ((bf16x4_t*)xb)[i] = o4;
    }
}

// ------------------------------------------------------- QKV projection GEMM
// R14 form (best-measured config, 136.8us overall with R16 out): 128x128
// tile, BK=32, single-buffer two-barrier structure, 512 threads = 8 waves.
// Wave grid 2m x 4n, sub-tile 64x32 (R17's 128x64 shrink was +0.7us —
// reverted). Q scale folds SM_SCALE*LOG2E -> attn uses raw exp2.
// Epilogue scatters into 32x32x16-MFMA operand-native layout:
//   Q (B-op): [h][qt][rb2][kc4][lane64][j8]  rb=(s&63)>>5, lane=(s&31)+((d>>3)&1)*32, kc=d>>4, j=d&7
//   K (A-op): same index function as Q
//   V (A-op, V^T): [h][kt][db2][kc4][lane64][j8] db=d>>5, lane=(d&31)+((key>>3)&1)*32, kc=(key&63)>>4, j=key&7
__global__ __launch_bounds__(512) void k_gemm_qkv(
    const __bf16* __restrict__ xb, const __bf16* __restrict__ wt,
    const float* __restrict__ bq, const float* __restrict__ bk, const float* __restrict__ bv,
    __bf16* __restrict__ qkv) {
    __shared__ __align__(16) unsigned short As[128 * 32];
    __shared__ __align__(16) unsigned short Bs[128 * 32];

    const int z = blockIdx.z;
    const __bf16* Bt = wt + (size_t)z * E_DIM * E_DIM;      // W^T [n][k]
    const float* bias = z == 0 ? bq : z == 1 ? bk : bv;
    __bf16* out = qkv + (size_t)z * NH * S_LEN * HD;

    const int tid = threadIdx.x, w = tid >> 6, l = tid & 63;
    const int lm = l & 15, q4 = l >> 4;
    const int bm = blockIdx.y, bn = blockIdx.x;
    const int wm = w >> 2, wn = w & 3;                      // 2x4 waves, 64x32 each

    const int sm = (w << 4) + (l >> 2);                     // staging row 0..127
    const int skk = (l & 3) << 3;
    const __bf16* Ag = xb + (size_t)(bm * 128 + sm) * E_DIM + skk;
    const __bf16* Bg = Bt + (size_t)(bn * 128 + sm) * E_DIM + skk;
    unsigned short* AsW = As + (w << 9);                    // w*1024 bytes
    unsigned short* BsW = Bs + (w << 9);

    f32x4_t acc[4][2];
#pragma unroll
    for (int i = 0; i < 4; i++)
#pragma unroll
        for (int j = 0; j < 2; j++) { acc[i][j].x = 0.f; acc[i][j].y = 0.f; acc[i][j].z = 0.f; acc[i][j].w = 0.f; }

    for (int k0 = 0; k0 < E_DIM; k0 += 32) {
        __syncthreads();
        GLD16(Ag + k0, AsW);
        GLD16(Bg + k0, BsW);
        __syncthreads();

        bf16x8_t af[4], bfr[2];
#pragma unroll
        for (int mt = 0; mt < 4; mt++)
            af[mt] = *(const bf16x8_t*)&As[(wm * 64 + mt * 16 + lm) * 32 + q4 * 8];
#pragma unroll
        for (int nt = 0; nt < 2; nt++)
            bfr[nt] = *(const bf16x8_t*)&Bs[(wn * 32 + nt * 16 + lm) * 32 + q4 * 8];
#pragma unroll
        for (int mt = 0; mt < 4; mt++)
#pragma unroll
            for (int nt = 0; nt < 2; nt++)
                acc[mt][nt] = __builtin_amdgcn_mfma_f32_16x16x32_bf16(af[mt], bfr[nt], acc[mt][nt], 0, 0, 0);
    }

    // C row s = bm*128 + wm*64 + mt*16 + q4*4 + i ; col n = bn*128 + wn*32 + nt*16 + lm
#pragma unroll
    for (int nt = 0; nt < 2; nt++) {
        const int n = bn * 128 + wn * 32 + nt * 16 + lm;
        const float bval = bias[n];
        const int h = n >> 6, d = n & 63;
        const int tile0 = bm * 2 + wm;          // s>>6
        if (z == 2) {
            // V A-op-native: key = mt*16 + q4*4 + i (local in tile)
            const int db = d >> 5, dl = d & 31;
#pragma unroll
            for (int mt = 0; mt < 4; mt++) {
                __bf16* ob = out + (((size_t)h * 32 + tile0) * 8 + db * 4 + mt) * 512
                                 + (dl + (q4 >> 1) * 32) * 8 + (q4 & 1) * 4;
                union { unsigned short s4[4]; uint2 u; } pk;
#pragma unroll
                for (int i = 0; i < 4; i++) pk.s4[i] = f2bf_bits(acc[mt][nt][i] + bval);
                *(uint2*)ob = pk.u;
            }
        } else {
            // Q/K op-native: s_local = mt*16 + q4*4 + i, rb = mt>>1
            // Q scale = SM_SCALE * LOG2E: attn computes exp2(S) = exp(S_orig*SM_SCALE)
            const float scale = (z == 0) ? (SM_SCALE * LOG2E) : 1.0f;
            const int kc = d >> 4, khalf = (d >> 3) & 1, j = d & 7;
#pragma unroll
            for (int mt = 0; mt < 4; mt++) {
                __bf16* ob = out + (((size_t)h * 32 + tile0) * 8 + (mt >> 1) * 4 + kc) * 512
                                 + ((mt & 1) * 16 + q4 * 4 + khalf * 32) * 8 + j;
#pragma unroll
                for (int i = 0; i < 4; i++)
                    ob[i * 8] = (__bf16)((acc[mt][nt][i] + bval) * scale);
            }
        }
    }
}

// ------------------------------------------------------------- attention
// R14 form (session best): 8-wave key-quarter split, 512 blocks x 512
// threads. Wave = (rh = w&1, kq = w>>1): rh picks 32 of the block's 64
// q-rows, kq picks 32 of the 128-key staging tile. 4 waves/SIMD (16
// waves/CU). Chunk maps: K chunk = kq*4+kc; V chunk = (kq>>1)*8 + db*4 +
// (kq&1)*2 + c. Causal: off = rowmin-base; skip iff off<-31, triangular iff
// off<=30. 4-way key partials combine linearly (no-max softmax, scores
// bounded). log2e pre-folded into Q -> raw exp2.
__global__ __launch_bounds__(512) void k_attn(
    const __bf16* __restrict__ Qf, const __bf16* __restrict__ Kf, const __bf16* __restrict__ Vf,
    __bf16* __restrict__ attn) {
    __shared__ __align__(16) unsigned short KVs[2][2][8192];  // [buf][K/V][16KB = 128 keys]

    // work-balanced swizzle: long q-tiles dispatched first
    const int b = blockIdx.x;
    int qt, h;
    if (b < 256) { qt = 16 + (b >> 4); h = b & 15; }
    else         { qt = 15 - ((b - 256) >> 4); h = (b - 256) & 15; }

    const int tid = threadIdx.x, w = tid >> 6, l = tid & 63;
    const int rh = w & 1, kq = w >> 1;          // 2 row-halves x 4 key-quarters
    const int l31 = l & 31, lh = l >> 5;

    const __bf16* Qb = Qf + ((size_t)h * 32 + qt) * 4096;
    const __bf16* Kb = Kf + (size_t)h * 32 * 4096;
    const __bf16* Vb = Vf + (size_t)h * 32 * 4096;

    // stage 128-key tile t: 16 K chunks + 16 V chunks of 1KB; wave w does 4
    auto stage = [&](int t, int buf) {
        const __bf16* Kg = Kb + (size_t)t * 8192;
        const __bf16* Vg = Vb + (size_t)t * 8192;
        GLD16(Kg + (w << 9) + l * 8,       &KVs[buf][0][(w << 9) + l * 8]);
        GLD16(Kg + ((w + 8) << 9) + l * 8, &KVs[buf][0][((w + 8) << 9) + l * 8]);
        GLD16(Vg + (w << 9) + l * 8,       &KVs[buf][1][(w << 9) + l * 8]);
        GLD16(Vg + ((w + 8) << 9) + l * 8, &KVs[buf][1][((w + 8) << 9) + l * 8]);
    };

    // Q B-frags pinned (pre-scaled by SM_SCALE*log2e): rows rh*32..+31
    bf16x8_t qf[4];
#pragma unroll
    for (int kc = 0; kc < 4; kc++)
        qf[kc] = *(const bf16x8_t*)(Qb + ((rh * 4 + kc) << 9) + l * 8);

    float lacc = 0.f;
    f32x16_t oacc[2];
#pragma unroll
    for (int db = 0; db < 2; db++)
#pragma unroll
        for (int r = 0; r < 16; r++) oacc[db][r] = 0.f;

    stage(0, 0);
    __syncthreads();

    const int ntiles = (qt >> 1) + 1;           // 128-key tiles to cover (qt+1)*64 keys
    const int rowmin = qt * 64 + rh * 32;       // this wave's lowest q-row

    for (int t = 0; t < ntiles; t++) {
        const int bb = t & 1;
        if (t + 1 < ntiles) stage(t + 1, bb ^ 1);

        const int base = t * 128 + kq * 32;     // wave's key base
        const int off = rowmin - base;          // >=31 plain; -31..30 tri; <-31 skip
        if (off >= -31) {
            // S^T = K·Q^T : D[keyl = (reg&3)+8*(reg>>2)+4*lh][row = l31]
            f32x16_t st;
#pragma unroll
            for (int r = 0; r < 16; r++) st[r] = 0.f;
            __builtin_amdgcn_s_setprio(1);
#pragma unroll
            for (int kc = 0; kc < 4; kc++) {
                bf16x8_t kf = *(const bf16x8_t*)&KVs[bb][0][((kq * 4 + kc) << 9) + l * 8];
                st = __builtin_amdgcn_mfma_f32_32x32x16_bf16(kf, qf[kc], st, 0, 0, 0);
            }
            __builtin_amdgcn_s_setprio(0);
            // exp2 (log2e folded into Q) + causal mask when tri
            if (off <= 30) {
#pragma unroll
                for (int r = 0; r < 16; r++) {
                    const int keyl = (r & 3) + 8 * (r >> 2) + 4 * lh;
                    st[r] = (keyl > off + l31) ? 0.f : __builtin_amdgcn_exp2f(st[r]);
                }
            } else {
#pragma unroll
                for (int r = 0; r < 16; r++) st[r] = __builtin_amdgcn_exp2f(st[r]);
            }
#pragma unroll
            for (int r = 0; r < 16; r++) lacc += st[r];
            // O^T += V^T·P : A = V frags, B = P frags built fully in-register.
            // c covers keys kq*32 + c*16 + {0..15}; st regs c*8..c*8+7 hold them.
#pragma unroll
            for (int c = 0; c < 2; c++) {
                unsigned int v0 = cvt_pk_bf16(st[c * 8 + 0], st[c * 8 + 1]);
                unsigned int v1 = cvt_pk_bf16(st[c * 8 + 2], st[c * 8 + 3]);
                unsigned int v2 = cvt_pk_bf16(st[c * 8 + 4], st[c * 8 + 5]);
                unsigned int v3 = cvt_pk_bf16(st[c * 8 + 6], st[c * 8 + 7]);
                // a' = [a.lo | b.lo], b' = [a.hi | b.hi] across the lane halves
                asm("v_permlane32_swap_b32 %0, %1" : "+v"(v0), "+v"(v2));
                asm("v_permlane32_swap_b32 %0, %1" : "+v"(v1), "+v"(v3));
                union { unsigned int u4[4]; bf16x8_t v; } pku;
                pku.u4[0] = v0; pku.u4[1] = v1; pku.u4[2] = v2; pku.u4[3] = v3;
                __builtin_amdgcn_s_setprio(1);
#pragma unroll
                for (int db = 0; db < 2; db++) {
                    const int vchunk = ((kq >> 1) * 8) + db * 4 + ((kq & 1) * 2) + c;
                    bf16x8_t vf = *(const bf16x8_t*)&KVs[bb][1][(vchunk << 9) + l * 8];
                    oacc[db] = __builtin_amdgcn_mfma_f32_32x32x16_bf16(vf, pku.v, oacc[db], 0, 0, 0);
                }
                __builtin_amdgcn_s_setprio(0);
            }
        }
        __syncthreads();   // reads of buf bb done; prefetch of bb^1 landed
    }

    // ---- key-quarter combine (linear: no-max softmax) ----
    // KVs reusable: all waves past the final loop barrier. Ex: per-lane
    // [rh*3 + (kq-1)][lane][34]: 32 O + lacc = 52KB <= 64KB.
    float* Ex = (float*)KVs;
    if (kq > 0) {
        float* e = Ex + (((rh * 3) + (kq - 1)) * 64 + l) * 34;
#pragma unroll
        for (int db = 0; db < 2; db++)
#pragma unroll
            for (int r = 0; r < 16; r++) e[db * 16 + r] = oacc[db][r];
        e[32] = lacc;
    }
    __syncthreads();
    if (kq == 0) {
#pragma unroll
        for (int p = 0; p < 3; p++) {
            const float* e = Ex + (((rh * 3) + p) * 64 + l) * 34;
#pragma unroll
            for (int db = 0; db < 2; db++)
#pragma unroll
                for (int r = 0; r < 16; r++) oacc[db][r] += e[db * 16 + r];
            lacc += e[32];
        }
        lacc += __shfl_xor(lacc, 32, 64);   // lanes l31 / l31+32 hold same row
        const float rl = 1.f / lacc;
        const int row = qt * 64 + rh * 32 + l31;
#pragma unroll
        for (int db = 0; db < 2; db++)
#pragma unroll
            for (int a = 0; a < 4; a++) {
                union { unsigned short s4[4]; uint2 u; } pk;
#pragma unroll
                for (int i = 0; i < 4; i++) pk.s4[i] = f2bf_bits(oacc[db][a * 4 + i] * rl);
                *(uint2*)(attn + (size_t)row * E_DIM + h * HD + db * 32 + a * 8 + lh * 4) = pk.u;
            }
    }
}

// --------------------------------------------------------- output projection
// R16 form (session best): 64x64 tile, grid 16x32 = 512 blocks = 2
// independent blocks/CU x 8 waves = 16 waves/CU. Double-buffered, 512
// threads. Wave grid 2m x 4n, sub-tile 32x16: af[2], bfr[1], acc[2],
// 2 MFMA/step/wave. Staging: waves 0..3 GLD16 As chunk w; waves 4..7
// GLD16 Bs chunk w-4. LDS 16KB.
__global__ __launch_bounds__(512) void k_gemm_out(
    const __bf16* __restrict__ A, const __bf16* __restrict__ Bt,
    const float* __restrict__ bias, float* __restrict__ out) {
    __shared__ __align__(16) unsigned short As[2][64 * 32];
    __shared__ __align__(16) unsigned short Bs[2][64 * 32];

    const int tid = threadIdx.x, w = tid >> 6, l = tid & 63;
    const int lm = l & 15, q4 = l >> 4;
    const int bm = blockIdx.y, bn = blockIdx.x;
    const int wm = w >> 2, wn = w & 3;                      // 2x4 waves, 32x16 each

    const int sc = w & 3;
    const int sm = (sc << 4) + (l >> 2);                    // chunk row 0..63
    const int skk = (l & 3) << 3;
    const __bf16* Ag = A + (size_t)(bm * 64 + sm) * E_DIM + skk;     // deref w<4 only
    const __bf16* Bg = Bt + (size_t)(bn * 64 + sm) * E_DIM + skk;    // deref w>=4 only
    const int coff = sc << 9;                               // 1KB chunk

    f32x4_t acc[2];
#pragma unroll
    for (int i = 0; i < 2; i++) { acc[i].x = 0.f; acc[i].y = 0.f; acc[i].z = 0.f; acc[i].w = 0.f; }

    if (w < 4) GLD16(Ag, &As[0][coff]);
    else       GLD16(Bg, &Bs[0][coff]);
    __syncthreads();

    for (int s = 0; s < 32; s++) {
        const int bb = s & 1;
        if (s < 31) {
            const int k0 = (s + 1) * 32;
            if (w < 4) GLD16(Ag + k0, &As[bb ^ 1][coff]);
            else       GLD16(Bg + k0, &Bs[bb ^ 1][coff]);
        }

        bf16x8_t af[2], bfr;
#pragma unroll
        for (int mt = 0; mt < 2; mt++)
            af[mt] = *(const bf16x8_t*)&As[bb][(wm * 32 + mt * 16 + lm) * 32 + q4 * 8];
        bfr = *(const bf16x8_t*)&Bs[bb][(wn * 16 + lm) * 32 + q4 * 8];
#pragma unroll
        for (int mt = 0; mt < 2; mt++)
            acc[mt] = __builtin_amdgcn_mfma_f32_16x16x32_bf16(af[mt], bfr, acc[mt], 0, 0, 0);
        __syncthreads();
    }

    {
        const int n = bn * 64 + wn * 16 + lm;
        const float bval = bias[n];
#pragma unroll
        for (int mt = 0; mt < 2; mt++) {
            const int r0 = bm * 64 + wm * 32 + mt * 16 + q4 * 4;
#pragma unroll
            for (int i = 0; i < 4; i++)
                out[(size_t)(r0 + i) * E_DIM + n] = acc[mt][i] + bval;
        }
    }
}

extern "C" void kernel_launch(void* const* d_in, const int* in_sizes, int n_in,
                              void* d_out, int out_size, void* d_ws, size_t ws_size,
                              hipStream_t stream) {
    const float* x  = (const float*)d_in[0];
    const float* Wq = (const float*)d_in[1];
    const float* bq = (const float*)d_in[2];
    const float* Wk = (const float*)d_in[3];
    const float* bk = (const float*)d_in[4];
    const float* Wv = (const float*)d_in[5];
    const float* bv = (const float*)d_in[6];
    const float* Wo = (const float*)d_in[7];
    const float* bo = (const float*)d_in[8];
    float* out = (float*)d_out;

    char* ws = (char*)d_ws;
    __bf16* xb   = (__bf16*)(ws);                        // 4 MB  x bf16 [S][E]
    __bf16* wt   = (__bf16*)(ws + ((size_t)4  << 20));   // 4x2MB [Wq^T,Wk^T,Wv^T,Wo^T] bf16
    __bf16* qkv  = (__bf16*)(ws + ((size_t)12 << 20));   // op-native Qf,Kf,Vf (4MB each)
    __bf16* attn = (__bf16*)(ws + ((size_t)24 << 20));   // 4 MB  [S][E] bf16

    k_prep<<<dim3(32, 32, 6), dim3(32, 8), 0, stream>>>(x, Wq, Wk, Wv, Wo, xb, wt);
    k_gemm_qkv<<<dim3(E_DIM / 128, S_LEN / 128, 3), 512, 0, stream>>>(xb, wt, bq, bk, bv, qkv);
    k_attn<<<dim3(512), 512, 0, stream>>>(
        qkv, qkv + (size_t)NH * S_LEN * HD, qkv + (size_t)2 * NH * S_LEN * HD, attn);
    k_gemm_out<<<dim3(E_DIM / 64, S_LEN / 64), 512, 0, stream>>>(
        attn, wt + (size_t)3 * E_DIM * E_DIM, bo, out);
}